// Round 1
// baseline (258.153 us; speedup 1.0000x reference)
//
#include <hip/hip_runtime.h>

// Problem constants
#define B_  2
#define S_  1024
#define FIN 768
#define E_  768
#define H_  12
#define DH  64   // = FH = 64

typedef unsigned int uint;
typedef unsigned short ushort;

__device__ __forceinline__ float bcast_lane(float v, int l) {
    return __uint_as_float((uint)__builtin_amdgcn_readlane((int)__float_as_uint(v), l));
}

__device__ __forceinline__ float wsum64(float v) {
#pragma unroll
    for (int m = 1; m < 64; m <<= 1) v += __shfl_xor(v, m, 64);
    return v;
}

// ---------------------------------------------------------------------------
// K2: xe = clip(x @ embed_w^T + b, 1e-6); inp = l1norm per (token, head)
// Tile: 128 tokens x 64 outputs (one head). Output layout: [(b*12+h)*1024+s][64]
// ---------------------------------------------------------------------------
__global__ __launch_bounds__(256) void k_embed(const float* __restrict__ xs,
                                               const float* __restrict__ ew,
                                               const float* __restrict__ eb,
                                               float* __restrict__ inp) {
    __shared__ float As[32][132]; // [k][token], pad row to 132 floats (16B-mult)
    __shared__ float Bs[32][68];  // [k][j]
    const int tid = threadIdx.x;
    const int tx = tid & 15;      // output quad  (4 outs)
    const int ty = tid >> 4;      // token octet  (8 tokens)
    const int head = blockIdx.y;
    const int tok0 = blockIdx.x * 128;

    float acc[8][4];
#pragma unroll
    for (int i = 0; i < 8; ++i)
#pragma unroll
        for (int j = 0; j < 4; ++j) acc[i][j] = 0.f;

    const int kc = tid & 7;   // k-chunk of 4 floats
    const int tA = tid >> 3;  // 0..31

    for (int kb = 0; kb < FIN; kb += 32) {
        // stage A: 128 x 32 floats
#pragma unroll
        for (int r = 0; r < 4; ++r) {
            int token = tA + 32 * r;
            float4 v = *(const float4*)(xs + (size_t)(tok0 + token) * FIN + kb + kc * 4);
            As[kc * 4 + 0][token] = v.x;
            As[kc * 4 + 1][token] = v.y;
            As[kc * 4 + 2][token] = v.z;
            As[kc * 4 + 3][token] = v.w;
        }
        // stage B: 64 x 32 floats
#pragma unroll
        for (int r = 0; r < 2; ++r) {
            int j = tA + 32 * r;
            float4 v = *(const float4*)(ew + (size_t)(head * 64 + j) * FIN + kb + kc * 4);
            Bs[kc * 4 + 0][j] = v.x;
            Bs[kc * 4 + 1][j] = v.y;
            Bs[kc * 4 + 2][j] = v.z;
            Bs[kc * 4 + 3][j] = v.w;
        }
        __syncthreads();
#pragma unroll 4
        for (int k = 0; k < 32; ++k) {
            float4 a0 = *(const float4*)&As[k][ty * 8];
            float4 a1 = *(const float4*)&As[k][ty * 8 + 4];
            float4 b4 = *(const float4*)&Bs[k][tx * 4];
            float av[8] = {a0.x, a0.y, a0.z, a0.w, a1.x, a1.y, a1.z, a1.w};
            float bv[4] = {b4.x, b4.y, b4.z, b4.w};
#pragma unroll
            for (int i = 0; i < 8; ++i)
#pragma unroll
                for (int j = 0; j < 4; ++j) acc[i][j] = fmaf(av[i], bv[j], acc[i][j]);
        }
        __syncthreads();
    }

    // epilogue: bias, clamp, l1-normalize over the 64 outputs of this head
    float bias[4];
#pragma unroll
    for (int j = 0; j < 4; ++j) bias[j] = eb[head * 64 + tx * 4 + j];

    float* red = &As[0][0];   // reuse: 16 x 132
    float* sums = &Bs[0][0];  // 128 floats
#pragma unroll
    for (int i = 0; i < 8; ++i) {
        float p = 0.f;
#pragma unroll
        for (int j = 0; j < 4; ++j) {
            float xe = fmaxf(acc[i][j] + bias[j], 1e-6f);
            acc[i][j] = xe;
            p += xe;
        }
        red[tx * 132 + ty * 8 + i] = p;
    }
    __syncthreads();
    if (tid < 128) {
        float s = 0.f;
#pragma unroll
        for (int t = 0; t < 16; ++t) s += red[t * 132 + tid];
        sums[tid] = fmaxf(s, 1e-20f);
    }
    __syncthreads();
#pragma unroll
    for (int i = 0; i < 8; ++i) {
        int tl = ty * 8 + i;
        float inv = 1.f / sums[tl];
        int g = tok0 + tl;
        int b = g >> 10, s = g & 1023;
        float4 o;
        o.x = acc[i][0] * inv; o.y = acc[i][1] * inv;
        o.z = acc[i][2] * inv; o.w = acc[i][3] * inv;
        *(float4*)(inp + ((size_t)((b * 12 + head) * 1024 + s)) * 64 + tx * 4) = o;
    }
}

// ---------------------------------------------------------------------------
// K3: NNMF multiplicative updates, one wave per token-head (4 per wave, seq.)
// W column d in VGPRs (wcol), W row f in VGPRs (wrow); h broadcast by readlane
// ---------------------------------------------------------------------------
__global__ __launch_bounds__(256) void k_nnmf(const float* __restrict__ inp,
                                              const float* __restrict__ nw,
                                              float* __restrict__ hout,
                                              float* __restrict__ hriout) {
    __shared__ float Wn[64 * 65];
    __shared__ float rs[64];
    const int tid = threadIdx.x;
    {   // stage nnmf_w -> LDS (stride 65), 16 floats/thread, same row per thread
        int e0 = tid * 16;
        int f = e0 >> 6, d0 = e0 & 63;
#pragma unroll
        for (int c4 = 0; c4 < 4; ++c4) {
            float4 v = *(const float4*)(nw + e0 + c4 * 4);
            Wn[f * 65 + d0 + c4 * 4 + 0] = v.x;
            Wn[f * 65 + d0 + c4 * 4 + 1] = v.y;
            Wn[f * 65 + d0 + c4 * 4 + 2] = v.z;
            Wn[f * 65 + d0 + c4 * 4 + 3] = v.w;
        }
    }
    __syncthreads();
    if (tid < 64) {
        float s = 0.f;
        for (int d = 0; d < 64; ++d) s += Wn[tid * 65 + d];
        rs[tid] = 1.f / fmaxf(s, 1e-20f);
    }
    __syncthreads();
    {
        int e0 = tid * 16;
        int f = e0 >> 6, d0 = e0 & 63;
        float sc = rs[f];
#pragma unroll
        for (int i = 0; i < 16; ++i) Wn[f * 65 + d0 + i] *= sc;
    }
    __syncthreads();

    const int lane = tid & 63;
    float wcol[64], wrow[64];
#pragma unroll
    for (int f = 0; f < 64; ++f) wcol[f] = Wn[f * 65 + lane];  // W[f][lane]
#pragma unroll
    for (int d = 0; d < 64; ++d) wrow[d] = Wn[lane * 65 + d];  // W[lane][d]

    const int wid = blockIdx.x * 4 + (tid >> 6);
    for (int tt = 0; tt < 4; ++tt) {
        const int th = wid * 4 + tt;           // token-head row, 0..24575
        const size_t base = (size_t)th * 64;
        float inpv = inp[base + lane];
        float h = 1.f / 64.f;
        float rec = 0.f;
        for (int it = 0; it < 3; ++it) {
            // t[lane=d] = sum_f h[f] * W[f][d]
            float t0 = 0, t1 = 0, t2 = 0, t3 = 0;
#pragma unroll
            for (int f = 0; f < 64; f += 4) {
                t0 = fmaf(bcast_lane(h, f + 0), wcol[f + 0], t0);
                t1 = fmaf(bcast_lane(h, f + 1), wcol[f + 1], t1);
                t2 = fmaf(bcast_lane(h, f + 2), wcol[f + 2], t2);
                t3 = fmaf(bcast_lane(h, f + 3), wcol[f + 3], t3);
            }
            float t = fmaxf((t0 + t1) + (t2 + t3), 1e-6f);
            rec = t / fmaxf(wsum64(t), 1e-20f);
            float q = inpv / rec;
            // u[lane=f] = sum_d q[d] * W[f][d]
            float u0 = 0, u1 = 0, u2 = 0, u3 = 0;
#pragma unroll
            for (int d = 0; d < 64; d += 4) {
                u0 = fmaf(bcast_lane(q, d + 0), wrow[d + 0], u0);
                u1 = fmaf(bcast_lane(q, d + 1), wrow[d + 1], u1);
                u2 = fmaf(bcast_lane(q, d + 2), wrow[d + 2], u2);
                u3 = fmaf(bcast_lane(q, d + 3), wrow[d + 3], u3);
            }
            float hn = fmaxf(h * ((u0 + u1) + (u2 + u3)), 1e-6f);
            h = hn / fmaxf(wsum64(hn), 1e-20f);
        }
        h = h / fmaxf(wsum64(h), 1e-20f);
        hout[base + lane] = h;
        hriout[base + lane] = rec * inpv;
    }
}

// ---------------------------------------------------------------------------
// K4: collapsed alpha dynamics. alpha[o,i] == c[o] (column-constant), so:
//   3x { m = h^T c ; v = 1/(m@W+eps) ; c[o] *= hri[o]·v } ; M = h^T c
// One block per (b,head), 1024 threads.
// ---------------------------------------------------------------------------
__global__ __launch_bounds__(1024) void k_alpha(const float* __restrict__ hin,
                                                const float* __restrict__ hri,
                                                const float* __restrict__ nw,
                                                float* __restrict__ Mout) {
    __shared__ float Wn[64 * 65];
    __shared__ float rsv[64];
    __shared__ float c[1024];
    __shared__ float mpart[16 * 64];
    __shared__ float mv[64];
    __shared__ float vv[64];
    const int tid = threadIdx.x;
    {   // stage nnmf_w: 4 floats/thread (same row)
        int e0 = tid * 4;
        int f = e0 >> 6, d0 = e0 & 63;
        float4 v = *(const float4*)(nw + e0);
        Wn[f * 65 + d0 + 0] = v.x;
        Wn[f * 65 + d0 + 1] = v.y;
        Wn[f * 65 + d0 + 2] = v.z;
        Wn[f * 65 + d0 + 3] = v.w;
    }
    __syncthreads();
    if (tid < 64) {
        float s = 0.f;
        for (int d = 0; d < 64; ++d) s += Wn[tid * 65 + d];
        rsv[tid] = 1.f / fmaxf(s, 1e-20f);
    }
    __syncthreads();
    {
        int e0 = tid * 4;
        int f = e0 >> 6, d0 = e0 & 63;
        float sc = rsv[f];
#pragma unroll
        for (int i = 0; i < 4; ++i) Wn[f * 65 + d0 + i] *= sc;
    }
    c[tid] = 1.f;
    __syncthreads();

    const size_t base = (size_t)blockIdx.x << 16;  // * 1024 * 64
    const int f = tid & 63, g = tid >> 6;

    for (int it = 0; it < 3; ++it) {
        // m-pass: m[f] = sum_o h[o,f] * c[o]
        float a = 0.f;
        const float* hp = hin + base + (size_t)(g * 64) * 64 + f;
#pragma unroll 8
        for (int o = 0; o < 64; ++o) a = fmaf(hp[o * 64], c[g * 64 + o], a);
        mpart[g * 64 + f] = a;
        __syncthreads();
        if (tid < 64) {
            float m = 0.f;
#pragma unroll
            for (int gg = 0; gg < 16; ++gg) m += mpart[gg * 64 + tid];
            mv[tid] = m;
        }
        __syncthreads();
        if (tid < 64) {
            float r = 0.f;
            for (int ff = 0; ff < 64; ++ff) r = fmaf(mv[ff], Wn[ff * 65 + tid], r);
            vv[tid] = 1.f / (r + 1e-20f);
        }
        __syncthreads();
        {
            const float* rp = hri + base + (size_t)tid * 64;
            float dot = 0.f;
#pragma unroll 8
            for (int d = 0; d < 64; ++d) dot = fmaf(rp[d], vv[d], dot);
            c[tid] *= dot;
        }
        __syncthreads();
    }
    // final m with c_3
    {
        float a = 0.f;
        const float* hp = hin + base + (size_t)(g * 64) * 64 + f;
#pragma unroll 8
        for (int o = 0; o < 64; ++o) a = fmaf(hp[o * 64], c[g * 64 + o], a);
        mpart[g * 64 + f] = a;
    }
    __syncthreads();
    if (tid < 64) {
        float m = 0.f;
#pragma unroll
        for (int gg = 0; gg < 16; ++gg) m += mpart[gg * 64 + tid];
        Mout[blockIdx.x * 64 + tid] = m;
    }
}

// ---------------------------------------------------------------------------
// K5a: y[b][j] = sum_e M[b][e]*out_w[j][e] + out_b[j]   (2 x 768 rows only)
// ---------------------------------------------------------------------------
__global__ __launch_bounds__(256) void k_proj(const float* __restrict__ M,
                                              const float* __restrict__ ow,
                                              const float* __restrict__ ob,
                                              float* __restrict__ y) {
    __shared__ float Ml[768];
    __shared__ float ps[4][64];
    const int tid = threadIdx.x;
    const int b = blockIdx.x / 12, jt = blockIdx.x % 12;
    for (int i = tid; i < 768; i += 256) Ml[i] = M[b * 768 + i];
    __syncthreads();
    const int jj = tid & 63, part = tid >> 6;
    const int j = jt * 64 + jj;
    const float* row = ow + (size_t)j * 768 + part * 192;
    float acc = 0.f;
    for (int t = 0; t < 192; t += 4) {
        float4 w4 = *(const float4*)(row + t);
        acc = fmaf(w4.x, Ml[part * 192 + t + 0], acc);
        acc = fmaf(w4.y, Ml[part * 192 + t + 1], acc);
        acc = fmaf(w4.z, Ml[part * 192 + t + 2], acc);
        acc = fmaf(w4.w, Ml[part * 192 + t + 3], acc);
    }
    ps[part][jj] = acc;
    __syncthreads();
    if (tid < 64) {
        float s = ps[0][tid] + ps[1][tid] + ps[2][tid] + ps[3][tid] + ob[jt * 64 + tid];
        y[b * 768 + jt * 64 + tid] = s;
    }
}

// ---------------------------------------------------------------------------
// K5b: broadcast y[b][:] to all 1024 sequence rows of the output
// ---------------------------------------------------------------------------
__global__ __launch_bounds__(256) void k_bcast(const float* __restrict__ y,
                                               float* __restrict__ out) {
    const int total = (B_ * S_ * FIN) / 4;  // float4 count
    for (int i = blockIdx.x * 256 + threadIdx.x; i < total; i += gridDim.x * 256) {
        int e0 = i * 4;
        int j = e0 % 768;
        int b = e0 / (1024 * 768);
        float4 v = *(const float4*)(y + b * 768 + j);
        *(float4*)(out + e0) = v;
    }
}

extern "C" void kernel_launch(void* const* d_in, const int* in_sizes, int n_in,
                              void* d_out, int out_size, void* d_ws, size_t ws_size,
                              hipStream_t stream) {
    const float* xs = (const float*)d_in[0];  // [2,1024,768]
    const float* ew = (const float*)d_in[1];  // [768,768]
    const float* eb = (const float*)d_in[2];  // [768]
    const float* nw = (const float*)d_in[3];  // [64,64]
    const float* ow = (const float*)d_in[4];  // [768,768]
    const float* ob = (const float*)d_in[5];  // [768]
    float* out = (float*)d_out;               // [2,1024,768]

    float* ws = (float*)d_ws;
    float* inp = ws;                 // 24576*64 = 1572864 floats
    float* h   = ws + 1572864;       // 1572864
    float* hri = ws + 3145728;       // 1572864
    float* M   = ws + 4718592;       // 1536
    float* y   = ws + 4720128;       // 1536

    k_embed<<<dim3(16, 12), 256, 0, stream>>>(xs, ew, eb, inp);
    k_nnmf<<<1536, 256, 0, stream>>>(inp, nw, h, hri);
    k_alpha<<<24, 1024, 0, stream>>>(h, hri, nw, M);
    k_proj<<<24, 256, 0, stream>>>(M, ow, ob, y);
    k_bcast<<<384, 256, 0, stream>>>(y, out);
}

// Round 2
// 217.157 us; speedup vs baseline: 1.1888x; 1.1888x over previous
//
#include <hip/hip_runtime.h>

// Problem constants
#define B_  2
#define S_  1024
#define FIN 768
#define E_  768
#define H_  12
#define DH  64   // = FH = 64

typedef unsigned int uint;
typedef unsigned short ushort;

__device__ __forceinline__ float bcast_lane(float v, int l) {
    return __uint_as_float((uint)__builtin_amdgcn_readlane((int)__float_as_uint(v), l));
}

__device__ __forceinline__ float wsum64(float v) {
#pragma unroll
    for (int m = 1; m < 64; m <<= 1) v += __shfl_xor(v, m, 64);
    return v;
}

// ---------------------------------------------------------------------------
// K2 v2: xe = clip(x @ embed_w^T + b, 1e-6); inp = l1norm per (token, head)
// Tile: 64 tokens x 64 outputs (one head), K-panels of 64.
// Grid 32x12 = 384 blocks (vs 192 before) for occupancy; shfl epilogue.
// Output layout: inp[(b*12+h)*1024+s][64]
// ---------------------------------------------------------------------------
__global__ __launch_bounds__(256) void k_embed(const float* __restrict__ xs,
                                               const float* __restrict__ ew,
                                               const float* __restrict__ eb,
                                               float* __restrict__ inp) {
    __shared__ float As[64][68];  // [k][token], stride 68 floats = 272B (16B mult)
    __shared__ float Bs[64][68];  // [k][out]
    const int tid = threadIdx.x;
    const int tx = tid & 15;      // out quad   (4 outs)
    const int ty = tid >> 4;      // token quad (4 tokens)
    const int head = blockIdx.y;
    const int tok0 = blockIdx.x * 64;

    float acc[4][4];
#pragma unroll
    for (int i = 0; i < 4; ++i)
#pragma unroll
        for (int j = 0; j < 4; ++j) acc[i][j] = 0.f;

    const int row = tid >> 2;          // 0..63 (token idx for A, out idx for B)
    const int kq = (tid & 3) * 16;     // k-offset of this thread's 16 floats
    const float* xrow = xs + (size_t)(tok0 + row) * FIN + kq;
    const float* wrow = ew + (size_t)(head * 64 + row) * FIN + kq;

    for (int kb = 0; kb < FIN; kb += 64) {
        // issue global loads BEFORE the barrier (prefetch overlap)
        float4 a4[4], b4[4];
#pragma unroll
        for (int c = 0; c < 4; ++c) {
            a4[c] = *(const float4*)(xrow + kb + c * 4);
            b4[c] = *(const float4*)(wrow + kb + c * 4);
        }
        __syncthreads();  // previous panel's compute done
#pragma unroll
        for (int c = 0; c < 4; ++c) {
            int k = kq + c * 4;
            As[k + 0][row] = a4[c].x; As[k + 1][row] = a4[c].y;
            As[k + 2][row] = a4[c].z; As[k + 3][row] = a4[c].w;
            Bs[k + 0][row] = b4[c].x; Bs[k + 1][row] = b4[c].y;
            Bs[k + 2][row] = b4[c].z; Bs[k + 3][row] = b4[c].w;
        }
        __syncthreads();
#pragma unroll 8
        for (int k = 0; k < 64; ++k) {
            float4 av = *(const float4*)&As[k][ty * 4];
            float4 bv = *(const float4*)&Bs[k][tx * 4];
            float a[4] = {av.x, av.y, av.z, av.w};
            float b[4] = {bv.x, bv.y, bv.z, bv.w};
#pragma unroll
            for (int i = 0; i < 4; ++i)
#pragma unroll
                for (int j = 0; j < 4; ++j) acc[i][j] = fmaf(a[i], b[j], acc[i][j]);
        }
    }

    // epilogue: bias, clamp, l1-normalize over the 64 outs of this head.
    // out-dim is spread over tx (16 lanes, xor-bits 0..3 of lane id).
    float bias[4];
#pragma unroll
    for (int j = 0; j < 4; ++j) bias[j] = eb[head * 64 + tx * 4 + j];

    float inv[4];
#pragma unroll
    for (int i = 0; i < 4; ++i) {
        float p = 0.f;
#pragma unroll
        for (int j = 0; j < 4; ++j) {
            float xe = fmaxf(acc[i][j] + bias[j], 1e-6f);
            acc[i][j] = xe;
            p += xe;
        }
        p += __shfl_xor(p, 1, 64);
        p += __shfl_xor(p, 2, 64);
        p += __shfl_xor(p, 4, 64);
        p += __shfl_xor(p, 8, 64);
        inv[i] = 1.f / fmaxf(p, 1e-20f);
    }
#pragma unroll
    for (int i = 0; i < 4; ++i) {
        int g = tok0 + ty * 4 + i;
        int b = g >> 10, s = g & 1023;
        float4 o;
        o.x = acc[i][0] * inv[i]; o.y = acc[i][1] * inv[i];
        o.z = acc[i][2] * inv[i]; o.w = acc[i][3] * inv[i];
        *(float4*)(inp + ((size_t)((b * 12 + head) * 1024 + s)) * 64 + tx * 4) = o;
    }
}

// ---------------------------------------------------------------------------
// K3: NNMF multiplicative updates, one wave per token-head (4 per wave, seq.)
// W column d in VGPRs (wcol), W row f in VGPRs (wrow); h broadcast by readlane
// ---------------------------------------------------------------------------
__global__ __launch_bounds__(256) void k_nnmf(const float* __restrict__ inp,
                                              const float* __restrict__ nw,
                                              float* __restrict__ hout,
                                              float* __restrict__ hriout) {
    __shared__ float Wn[64 * 65];
    __shared__ float rs[64];
    const int tid = threadIdx.x;
    {   // stage nnmf_w -> LDS (stride 65), 16 floats/thread, same row per thread
        int e0 = tid * 16;
        int f = e0 >> 6, d0 = e0 & 63;
#pragma unroll
        for (int c4 = 0; c4 < 4; ++c4) {
            float4 v = *(const float4*)(nw + e0 + c4 * 4);
            Wn[f * 65 + d0 + c4 * 4 + 0] = v.x;
            Wn[f * 65 + d0 + c4 * 4 + 1] = v.y;
            Wn[f * 65 + d0 + c4 * 4 + 2] = v.z;
            Wn[f * 65 + d0 + c4 * 4 + 3] = v.w;
        }
    }
    __syncthreads();
    if (tid < 64) {
        float s = 0.f;
        for (int d = 0; d < 64; ++d) s += Wn[tid * 65 + d];
        rs[tid] = 1.f / fmaxf(s, 1e-20f);
    }
    __syncthreads();
    {
        int e0 = tid * 16;
        int f = e0 >> 6, d0 = e0 & 63;
        float sc = rs[f];
#pragma unroll
        for (int i = 0; i < 16; ++i) Wn[f * 65 + d0 + i] *= sc;
    }
    __syncthreads();

    const int lane = tid & 63;
    float wcol[64], wrow[64];
#pragma unroll
    for (int f = 0; f < 64; ++f) wcol[f] = Wn[f * 65 + lane];  // W[f][lane]
#pragma unroll
    for (int d = 0; d < 64; ++d) wrow[d] = Wn[lane * 65 + d];  // W[lane][d]

    const int wid = blockIdx.x * 4 + (tid >> 6);
    for (int tt = 0; tt < 4; ++tt) {
        const int th = wid * 4 + tt;           // token-head row, 0..24575
        const size_t base = (size_t)th * 64;
        float inpv = inp[base + lane];
        float h = 1.f / 64.f;
        float rec = 0.f;
        for (int it = 0; it < 3; ++it) {
            // t[lane=d] = sum_f h[f] * W[f][d]
            float t0 = 0, t1 = 0, t2 = 0, t3 = 0;
#pragma unroll
            for (int f = 0; f < 64; f += 4) {
                t0 = fmaf(bcast_lane(h, f + 0), wcol[f + 0], t0);
                t1 = fmaf(bcast_lane(h, f + 1), wcol[f + 1], t1);
                t2 = fmaf(bcast_lane(h, f + 2), wcol[f + 2], t2);
                t3 = fmaf(bcast_lane(h, f + 3), wcol[f + 3], t3);
            }
            float t = fmaxf((t0 + t1) + (t2 + t3), 1e-6f);
            rec = t / fmaxf(wsum64(t), 1e-20f);
            float q = inpv / rec;
            // u[lane=f] = sum_d q[d] * W[f][d]
            float u0 = 0, u1 = 0, u2 = 0, u3 = 0;
#pragma unroll
            for (int d = 0; d < 64; d += 4) {
                u0 = fmaf(bcast_lane(q, d + 0), wrow[d + 0], u0);
                u1 = fmaf(bcast_lane(q, d + 1), wrow[d + 1], u1);
                u2 = fmaf(bcast_lane(q, d + 2), wrow[d + 2], u2);
                u3 = fmaf(bcast_lane(q, d + 3), wrow[d + 3], u3);
            }
            float hn = fmaxf(h * ((u0 + u1) + (u2 + u3)), 1e-6f);
            h = hn / fmaxf(wsum64(hn), 1e-20f);
        }
        h = h / fmaxf(wsum64(h), 1e-20f);
        hout[base + lane] = h;
        hriout[base + lane] = rec * inpv;
    }
}

// ---------------------------------------------------------------------------
// K4 v2: collapsed alpha dynamics; h column cached in VGPRs (reused 4x).
//   3x { m = h^T c ; v = 1/(m@W+eps) ; c[o] *= hri[o]·v } ; M = h^T c
// One block per (b,head), 1024 threads, <=128 VGPR (16 waves must co-reside).
// ---------------------------------------------------------------------------
__global__ __launch_bounds__(1024, 4) void k_alpha(const float* __restrict__ hin,
                                                   const float* __restrict__ hri,
                                                   const float* __restrict__ nw,
                                                   float* __restrict__ Mout) {
    __shared__ float Wn[64 * 65];
    __shared__ float rsv[64];
    __shared__ float c[1024];
    __shared__ float mpart[16 * 64];
    __shared__ float mv[64];
    __shared__ float vv[64];
    const int tid = threadIdx.x;
    {   // stage nnmf_w: 4 floats/thread (same row)
        int e0 = tid * 4;
        int f = e0 >> 6, d0 = e0 & 63;
        float4 v = *(const float4*)(nw + e0);
        Wn[f * 65 + d0 + 0] = v.x;
        Wn[f * 65 + d0 + 1] = v.y;
        Wn[f * 65 + d0 + 2] = v.z;
        Wn[f * 65 + d0 + 3] = v.w;
    }
    __syncthreads();
    if (tid < 64) {
        float s = 0.f;
        for (int d = 0; d < 64; ++d) s += Wn[tid * 65 + d];
        rsv[tid] = 1.f / fmaxf(s, 1e-20f);
    }
    __syncthreads();
    {
        int e0 = tid * 4;
        int f = e0 >> 6, d0 = e0 & 63;
        float sc = rsv[f];
#pragma unroll
        for (int i = 0; i < 4; ++i) Wn[f * 65 + d0 + i] *= sc;
    }
    c[tid] = 1.f;

    const size_t base = (size_t)blockIdx.x << 16;  // * 1024 * 64
    const int f = tid & 63, g = tid >> 6;

    // cache this thread's h column slice: h[(g*64+o)][f], o=0..63 (reused 4x)
    float hreg[64];
    {
        const float* hp = hin + base + (size_t)(g * 64) * 64 + f;
#pragma unroll
        for (int o = 0; o < 64; ++o) hreg[o] = hp[o * 64];
    }
    __syncthreads();

    for (int it = 0; it < 3; ++it) {
        // m-pass: m[f] = sum_o h[o,f] * c[o]
        float a = 0.f;
#pragma unroll
        for (int o = 0; o < 64; ++o) a = fmaf(hreg[o], c[g * 64 + o], a);
        mpart[g * 64 + f] = a;
        __syncthreads();
        if (tid < 64) {
            float m = 0.f;
#pragma unroll
            for (int gg = 0; gg < 16; ++gg) m += mpart[gg * 64 + tid];
            mv[tid] = m;
        }
        __syncthreads();
        if (tid < 64) {
            float r = 0.f;
            for (int ff = 0; ff < 64; ++ff) r = fmaf(mv[ff], Wn[ff * 65 + tid], r);
            vv[tid] = 1.f / (r + 1e-20f);
        }
        __syncthreads();
        {
            const float* rp = hri + base + (size_t)tid * 64;
            float dot = 0.f;
#pragma unroll
            for (int d4 = 0; d4 < 64; d4 += 4) {
                float4 r4 = *(const float4*)(rp + d4);
                dot = fmaf(r4.x, vv[d4 + 0], dot);
                dot = fmaf(r4.y, vv[d4 + 1], dot);
                dot = fmaf(r4.z, vv[d4 + 2], dot);
                dot = fmaf(r4.w, vv[d4 + 3], dot);
            }
            c[tid] *= dot;
        }
        __syncthreads();
    }
    // final m with c_3
    {
        float a = 0.f;
#pragma unroll
        for (int o = 0; o < 64; ++o) a = fmaf(hreg[o], c[g * 64 + o], a);
        mpart[g * 64 + f] = a;
    }
    __syncthreads();
    if (tid < 64) {
        float m = 0.f;
#pragma unroll
        for (int gg = 0; gg < 16; ++gg) m += mpart[gg * 64 + tid];
        Mout[blockIdx.x * 64 + tid] = m;
    }
}

// ---------------------------------------------------------------------------
// K5a: y[b][j] = sum_e M[b][e]*out_w[j][e] + out_b[j]   (2 x 768 rows only)
// ---------------------------------------------------------------------------
__global__ __launch_bounds__(256) void k_proj(const float* __restrict__ M,
                                              const float* __restrict__ ow,
                                              const float* __restrict__ ob,
                                              float* __restrict__ y) {
    __shared__ float Ml[768];
    __shared__ float ps[4][64];
    const int tid = threadIdx.x;
    const int b = blockIdx.x / 12, jt = blockIdx.x % 12;
    for (int i = tid; i < 768; i += 256) Ml[i] = M[b * 768 + i];
    __syncthreads();
    const int jj = tid & 63, part = tid >> 6;
    const int j = jt * 64 + jj;
    const float* row = ow + (size_t)j * 768 + part * 192;
    float acc = 0.f;
    for (int t = 0; t < 192; t += 4) {
        float4 w4 = *(const float4*)(row + t);
        acc = fmaf(w4.x, Ml[part * 192 + t + 0], acc);
        acc = fmaf(w4.y, Ml[part * 192 + t + 1], acc);
        acc = fmaf(w4.z, Ml[part * 192 + t + 2], acc);
        acc = fmaf(w4.w, Ml[part * 192 + t + 3], acc);
    }
    ps[part][jj] = acc;
    __syncthreads();
    if (tid < 64) {
        float s = ps[0][tid] + ps[1][tid] + ps[2][tid] + ps[3][tid] + ob[jt * 64 + tid];
        y[b * 768 + jt * 64 + tid] = s;
    }
}

// ---------------------------------------------------------------------------
// K5b: broadcast y[b][:] to all 1024 sequence rows of the output
// ---------------------------------------------------------------------------
__global__ __launch_bounds__(256) void k_bcast(const float* __restrict__ y,
                                               float* __restrict__ out) {
    const int total = (B_ * S_ * FIN) / 4;  // float4 count
    for (int i = blockIdx.x * 256 + threadIdx.x; i < total; i += gridDim.x * 256) {
        int e0 = i * 4;
        int j = e0 % 768;
        int b = e0 / (1024 * 768);
        float4 v = *(const float4*)(y + b * 768 + j);
        *(float4*)(out + e0) = v;
    }
}

extern "C" void kernel_launch(void* const* d_in, const int* in_sizes, int n_in,
                              void* d_out, int out_size, void* d_ws, size_t ws_size,
                              hipStream_t stream) {
    const float* xs = (const float*)d_in[0];  // [2,1024,768]
    const float* ew = (const float*)d_in[1];  // [768,768]
    const float* eb = (const float*)d_in[2];  // [768]
    const float* nw = (const float*)d_in[3];  // [64,64]
    const float* ow = (const float*)d_in[4];  // [768,768]
    const float* ob = (const float*)d_in[5];  // [768]
    float* out = (float*)d_out;               // [2,1024,768]

    float* ws = (float*)d_ws;
    float* inp = ws;                 // 24576*64 = 1572864 floats
    float* h   = ws + 1572864;       // 1572864
    float* hri = ws + 3145728;       // 1572864
    float* M   = ws + 4718592;       // 1536
    float* y   = ws + 4720128;       // 1536

    k_embed<<<dim3(32, 12), 256, 0, stream>>>(xs, ew, eb, inp);
    k_nnmf<<<1536, 256, 0, stream>>>(inp, nw, h, hri);
    k_alpha<<<24, 1024, 0, stream>>>(h, hri, nw, M);
    k_proj<<<24, 256, 0, stream>>>(M, ow, ob, y);
    k_bcast<<<384, 256, 0, stream>>>(y, out);
}

// Round 3
// 207.650 us; speedup vs baseline: 1.2432x; 1.0458x over previous
//
#include <hip/hip_runtime.h>

// Problem constants
#define B_  2
#define S_  1024
#define FIN 768
#define E_  768
#define H_  12
#define DH  64   // = FH = 64

typedef unsigned int uint;
typedef unsigned short ushort;

__device__ __forceinline__ float bcast_lane(float v, int l) {
    return __uint_as_float((uint)__builtin_amdgcn_readlane((int)__float_as_uint(v), l));
}

__device__ __forceinline__ float wsum64(float v) {
#pragma unroll
    for (int m = 1; m < 64; m <<= 1) v += __shfl_xor(v, m, 64);
    return v;
}

// ---------------------------------------------------------------------------
// K2 v3: xe = clip(x @ embed_w^T + b, 1e-6); inp = l1norm per (token, head)
// Tile 64 tok x 64 out (one head); 256 threads = 4 waves, each wave owns a
// 16-wide k-quarter of every 64-k panel with an 8x8 per-thread tile
// (4 ds_read_b128 per 64 FMA -> LDS issue ratio 1.5 vs 3.0 before).
// Cross-wave partial-acc reduction + bias/clamp/l1norm epilogue in LDS.
// ---------------------------------------------------------------------------
__global__ __launch_bounds__(256) void k_embed(const float* __restrict__ xs,
                                               const float* __restrict__ ew,
                                               const float* __restrict__ eb,
                                               float* __restrict__ inp) {
    __shared__ float smem[4 * 64 * 68];  // 69.6 KB; aliases As/Bs then Red
    float* As = smem;                    // [64][68] (k-major)
    float* Bs = smem + 64 * 68;          // [64][68]
    const int tid = threadIdx.x;
    const int head = blockIdx.y;
    const int tok0 = blockIdx.x * 64;
    const int wv = tid >> 6;             // wave id 0..3 -> k-quarter
    const int lane = tid & 63;
    const int j0 = (lane & 7) * 8;       // 8 outs
    const int t0 = (lane >> 3) * 8;      // 8 tokens

    float acc[8][8];
#pragma unroll
    for (int i = 0; i < 8; ++i)
#pragma unroll
        for (int j = 0; j < 8; ++j) acc[i][j] = 0.f;

    const int row = tid >> 2;            // 0..63
    const int kq = (tid & 3) * 16;
    const float* xrow = xs + (size_t)(tok0 + row) * FIN + kq;
    const float* wrow = ew + (size_t)(head * 64 + row) * FIN + kq;

    for (int kb = 0; kb < FIN; kb += 64) {
        float4 a4[4], b4[4];
#pragma unroll
        for (int c = 0; c < 4; ++c) {
            a4[c] = *(const float4*)(xrow + kb + c * 4);
            b4[c] = *(const float4*)(wrow + kb + c * 4);
        }
        __syncthreads();  // all waves done computing previous panel
#pragma unroll
        for (int c = 0; c < 4; ++c) {
            int k = kq + c * 4;
            As[(k + 0) * 68 + row] = a4[c].x; As[(k + 1) * 68 + row] = a4[c].y;
            As[(k + 2) * 68 + row] = a4[c].z; As[(k + 3) * 68 + row] = a4[c].w;
            Bs[(k + 0) * 68 + row] = b4[c].x; Bs[(k + 1) * 68 + row] = b4[c].y;
            Bs[(k + 2) * 68 + row] = b4[c].z; Bs[(k + 3) * 68 + row] = b4[c].w;
        }
        __syncthreads();
        const int k0 = wv * 16;
#pragma unroll
        for (int kk = 0; kk < 16; ++kk) {
            const int k = k0 + kk;
            float4 av0 = *(const float4*)&As[k * 68 + t0];
            float4 av1 = *(const float4*)&As[k * 68 + t0 + 4];
            float4 bv0 = *(const float4*)&Bs[k * 68 + j0];
            float4 bv1 = *(const float4*)&Bs[k * 68 + j0 + 4];
            float a[8] = {av0.x, av0.y, av0.z, av0.w, av1.x, av1.y, av1.z, av1.w};
            float b[8] = {bv0.x, bv0.y, bv0.z, bv0.w, bv1.x, bv1.y, bv1.z, bv1.w};
#pragma unroll
            for (int i = 0; i < 8; ++i)
#pragma unroll
                for (int j = 0; j < 8; ++j) acc[i][j] = fmaf(a[i], b[j], acc[i][j]);
        }
    }
    __syncthreads();  // everyone done reading As/Bs before Red clobbers them

    // write this wave's partial 64x64 tile to Red[wv]
    float* Red = smem;  // [4][64][68]
#pragma unroll
    for (int i = 0; i < 8; ++i) {
        *(float4*)&Red[((size_t)wv * 64 + t0 + i) * 68 + j0] =
            make_float4(acc[i][0], acc[i][1], acc[i][2], acc[i][3]);
        *(float4*)&Red[((size_t)wv * 64 + t0 + i) * 68 + j0 + 4] =
            make_float4(acc[i][4], acc[i][5], acc[i][6], acc[i][7]);
    }
    __syncthreads();

    // reduce 4 k-partials + bias + clamp + l1norm + store
    const int t = tid >> 2;       // token 0..63
    const int q = tid & 3;        // 16-out quarter
    float4 r[4];
    float psum = 0.f;
#pragma unroll
    for (int c4 = 0; c4 < 4; ++c4) {
        int j = q * 16 + c4 * 4;
        float4 s0 = *(const float4*)&Red[((size_t)0 * 64 + t) * 68 + j];
        float4 s1 = *(const float4*)&Red[((size_t)1 * 64 + t) * 68 + j];
        float4 s2 = *(const float4*)&Red[((size_t)2 * 64 + t) * 68 + j];
        float4 s3 = *(const float4*)&Red[((size_t)3 * 64 + t) * 68 + j];
        float4 bb = *(const float4*)(eb + head * 64 + j);
        float4 v;
        v.x = fmaxf(((s0.x + s1.x) + (s2.x + s3.x)) + bb.x, 1e-6f);
        v.y = fmaxf(((s0.y + s1.y) + (s2.y + s3.y)) + bb.y, 1e-6f);
        v.z = fmaxf(((s0.z + s1.z) + (s2.z + s3.z)) + bb.z, 1e-6f);
        v.w = fmaxf(((s0.w + s1.w) + (s2.w + s3.w)) + bb.w, 1e-6f);
        psum += (v.x + v.y) + (v.z + v.w);
        r[c4] = v;
    }
    psum += __shfl_xor(psum, 1, 64);
    psum += __shfl_xor(psum, 2, 64);
    const float inv = 1.f / fmaxf(psum, 1e-20f);
    const int g = tok0 + t;
    const int b = g >> 10, s = g & 1023;
    float* op = inp + ((size_t)((b * 12 + head) * 1024 + s)) * 64 + q * 16;
#pragma unroll
    for (int c4 = 0; c4 < 4; ++c4) {
        float4 o;
        o.x = r[c4].x * inv; o.y = r[c4].y * inv;
        o.z = r[c4].z * inv; o.w = r[c4].w * inv;
        *(float4*)(op + c4 * 4) = o;
    }
}

// ---------------------------------------------------------------------------
// K3: NNMF multiplicative updates, one wave per token-head (4 per wave, seq.)
// ---------------------------------------------------------------------------
__global__ __launch_bounds__(256) void k_nnmf(const float* __restrict__ inp,
                                              const float* __restrict__ nw,
                                              float* __restrict__ hout,
                                              float* __restrict__ hriout) {
    __shared__ float Wn[64 * 65];
    __shared__ float rs[64];
    const int tid = threadIdx.x;
    {   // stage nnmf_w -> LDS (stride 65)
        int e0 = tid * 16;
        int f = e0 >> 6, d0 = e0 & 63;
#pragma unroll
        for (int c4 = 0; c4 < 4; ++c4) {
            float4 v = *(const float4*)(nw + e0 + c4 * 4);
            Wn[f * 65 + d0 + c4 * 4 + 0] = v.x;
            Wn[f * 65 + d0 + c4 * 4 + 1] = v.y;
            Wn[f * 65 + d0 + c4 * 4 + 2] = v.z;
            Wn[f * 65 + d0 + c4 * 4 + 3] = v.w;
        }
    }
    __syncthreads();
    if (tid < 64) {
        float s = 0.f;
        for (int d = 0; d < 64; ++d) s += Wn[tid * 65 + d];
        rs[tid] = 1.f / fmaxf(s, 1e-20f);
    }
    __syncthreads();
    {
        int e0 = tid * 16;
        int f = e0 >> 6, d0 = e0 & 63;
        float sc = rs[f];
#pragma unroll
        for (int i = 0; i < 16; ++i) Wn[f * 65 + d0 + i] *= sc;
    }
    __syncthreads();

    const int lane = tid & 63;
    float wcol[64], wrow[64];
#pragma unroll
    for (int f = 0; f < 64; ++f) wcol[f] = Wn[f * 65 + lane];  // W[f][lane]
#pragma unroll
    for (int d = 0; d < 64; ++d) wrow[d] = Wn[lane * 65 + d];  // W[lane][d]

    const int wid = blockIdx.x * 4 + (tid >> 6);
    for (int tt = 0; tt < 4; ++tt) {
        const int th = wid * 4 + tt;
        const size_t base = (size_t)th * 64;
        float inpv = inp[base + lane];
        float h = 1.f / 64.f;
        float rec = 0.f;
        for (int it = 0; it < 3; ++it) {
            float t0 = 0, t1 = 0, t2 = 0, t3 = 0;
#pragma unroll
            for (int f = 0; f < 64; f += 4) {
                t0 = fmaf(bcast_lane(h, f + 0), wcol[f + 0], t0);
                t1 = fmaf(bcast_lane(h, f + 1), wcol[f + 1], t1);
                t2 = fmaf(bcast_lane(h, f + 2), wcol[f + 2], t2);
                t3 = fmaf(bcast_lane(h, f + 3), wcol[f + 3], t3);
            }
            float t = fmaxf((t0 + t1) + (t2 + t3), 1e-6f);
            rec = t / fmaxf(wsum64(t), 1e-20f);
            float q = inpv / rec;
            float u0 = 0, u1 = 0, u2 = 0, u3 = 0;
#pragma unroll
            for (int d = 0; d < 64; d += 4) {
                u0 = fmaf(bcast_lane(q, d + 0), wrow[d + 0], u0);
                u1 = fmaf(bcast_lane(q, d + 1), wrow[d + 1], u1);
                u2 = fmaf(bcast_lane(q, d + 2), wrow[d + 2], u2);
                u3 = fmaf(bcast_lane(q, d + 3), wrow[d + 3], u3);
            }
            float hn = fmaxf(h * ((u0 + u1) + (u2 + u3)), 1e-6f);
            h = hn / fmaxf(wsum64(hn), 1e-20f);
        }
        h = h / fmaxf(wsum64(h), 1e-20f);
        hout[base + lane] = h;
        hriout[base + lane] = rec * inpv;
    }
}

// ---------------------------------------------------------------------------
// K4 v3: one alpha iteration per launch, 384 blocks = (bh 0..23) x (chunk 0..15).
// Each block: [it>0] m = sum of 16 chunk-partials (prev launch), v = 1/(mW+eps)
// (redundant per block), update its 64-o c-chunk; then emit new partial m.
// Double-buffered partials; c persists in global between launches.
// ---------------------------------------------------------------------------
__global__ __launch_bounds__(256) void k_alpha_step(const float* __restrict__ hin,
                                                    const float* __restrict__ hri,
                                                    const float* __restrict__ nw,
                                                    const float* __restrict__ mp_in,
                                                    float* __restrict__ mp_out,
                                                    float* __restrict__ c,
                                                    int it) {
    __shared__ float Wn[64 * 65];
    __shared__ float rs[64];
    __shared__ float mred[4][64];
    __shared__ float mv[64];
    __shared__ float vv[64];
    __shared__ float cl[64];
    const int tid = threadIdx.x;
    const int bh = blockIdx.x >> 4;
    const int chunk = blockIdx.x & 15;
    const size_t rowbase = (size_t)bh * 1024 + chunk * 64;  // first o-row

    {   // stage nnmf_w (stride 65)
        int e0 = tid * 16;
        int f = e0 >> 6, d0 = e0 & 63;
#pragma unroll
        for (int c4 = 0; c4 < 4; ++c4) {
            float4 v = *(const float4*)(nw + e0 + c4 * 4);
            Wn[f * 65 + d0 + c4 * 4 + 0] = v.x;
            Wn[f * 65 + d0 + c4 * 4 + 1] = v.y;
            Wn[f * 65 + d0 + c4 * 4 + 2] = v.z;
            Wn[f * 65 + d0 + c4 * 4 + 3] = v.w;
        }
    }
    __syncthreads();
    if (tid < 64) {
        float s = 0.f;
        for (int d = 0; d < 64; ++d) s += Wn[tid * 65 + d];
        rs[tid] = 1.f / fmaxf(s, 1e-20f);
    }
    __syncthreads();
    {
        int e0 = tid * 16;
        int f = e0 >> 6, d0 = e0 & 63;
        float sc = rs[f];
#pragma unroll
        for (int i = 0; i < 16; ++i) Wn[f * 65 + d0 + i] *= sc;
    }

    if (it > 0) {
        // m[f] = sum over 16 chunks of mp_in[bh][ch][f]
        {
            int f = tid & 63, p = tid >> 6;
            float s = 0.f;
#pragma unroll
            for (int pp = 0; pp < 4; ++pp)
                s += mp_in[((size_t)bh * 16 + p * 4 + pp) * 64 + f];
            mred[p][f] = s;
        }
        __syncthreads();  // also fences Wn scaling
        if (tid < 64)
            mv[tid] = (mred[0][tid] + mred[1][tid]) + (mred[2][tid] + mred[3][tid]);
        __syncthreads();
        // v[d] = 1/(sum_f m[f]*W[f][d] + eps)
        {
            int d = tid & 63, qq = tid >> 6;
            float r = 0.f;
#pragma unroll
            for (int f = 0; f < 16; ++f) r = fmaf(mv[qq * 16 + f], Wn[(qq * 16 + f) * 65 + d], r);
            mred[qq][d] = r;
        }
        __syncthreads();
        if (tid < 64)
            vv[tid] = 1.f / (((mred[0][tid] + mred[1][tid]) + (mred[2][tid] + mred[3][tid])) + 1e-20f);
        __syncthreads();
        // c-update: c[o] *= dot(hri[o,:], v)
        {
            int o = tid >> 2, dq = tid & 3;
            const float* rp = hri + (rowbase + o) * 64 + dq * 16;
            float dot = 0.f;
#pragma unroll
            for (int t4 = 0; t4 < 16; t4 += 4) {
                float4 r4 = *(const float4*)(rp + t4);
                dot = fmaf(r4.x, vv[dq * 16 + t4 + 0], dot);
                dot = fmaf(r4.y, vv[dq * 16 + t4 + 1], dot);
                dot = fmaf(r4.z, vv[dq * 16 + t4 + 2], dot);
                dot = fmaf(r4.w, vv[dq * 16 + t4 + 3], dot);
            }
            dot += __shfl_xor(dot, 1, 64);
            dot += __shfl_xor(dot, 2, 64);
            float cn = dot;
            if (it >= 2) cn *= c[rowbase + o];
            if (dq == 0) { c[rowbase + o] = cn; cl[o] = cn; }
        }
        __syncthreads();
    } else {
        if (tid < 64) cl[tid] = 1.f;
        __syncthreads();
    }

    // partial m for this chunk: m_c[f] = sum_{o in chunk} h[o,f] * cl[o]
    {
        const int f4 = (tid & 15) * 4, og = tid >> 4;
        float4 a = make_float4(0.f, 0.f, 0.f, 0.f);
#pragma unroll
        for (int oi = 0; oi < 4; ++oi) {
            int o = og * 4 + oi;
            float4 h4 = *(const float4*)(hin + (rowbase + o) * 64 + f4);
            float cv = cl[o];
            a.x = fmaf(h4.x, cv, a.x); a.y = fmaf(h4.y, cv, a.y);
            a.z = fmaf(h4.z, cv, a.z); a.w = fmaf(h4.w, cv, a.w);
        }
        a.x += __shfl_xor(a.x, 16, 64); a.y += __shfl_xor(a.y, 16, 64);
        a.z += __shfl_xor(a.z, 16, 64); a.w += __shfl_xor(a.w, 16, 64);
        a.x += __shfl_xor(a.x, 32, 64); a.y += __shfl_xor(a.y, 32, 64);
        a.z += __shfl_xor(a.z, 32, 64); a.w += __shfl_xor(a.w, 32, 64);
        const int w = tid >> 6;
        if ((tid & 63) < 16) *(float4*)&mred[w][(tid & 15) * 4] = a;
    }
    __syncthreads();
    if (tid < 64)
        mp_out[((size_t)bh * 16 + chunk) * 64 + tid] =
            (mred[0][tid] + mred[1][tid]) + (mred[2][tid] + mred[3][tid]);
}

// ---------------------------------------------------------------------------
// K5a: y[b][j] = sum_e M[b][e]*out_w[j][e] + out_b[j]; M summed from 16 chunk
// partials of the final alpha launch.
// ---------------------------------------------------------------------------
__global__ __launch_bounds__(256) void k_proj(const float* __restrict__ mpM,
                                              const float* __restrict__ ow,
                                              const float* __restrict__ ob,
                                              float* __restrict__ y) {
    __shared__ float Ml[768];
    __shared__ float ps[4][64];
    const int tid = threadIdx.x;
    const int b = blockIdx.x / 12, jt = blockIdx.x % 12;
    for (int i = tid; i < 768; i += 256) {
        int hh = i >> 6, f = i & 63;
        const float* mp = mpM + ((size_t)(b * 12 + hh) * 16) * 64 + f;
        float s = 0.f;
#pragma unroll
        for (int ch = 0; ch < 16; ++ch) s += mp[ch * 64];
        Ml[i] = s;
    }
    __syncthreads();
    const int jj = tid & 63, part = tid >> 6;
    const int j = jt * 64 + jj;
    const float* row = ow + (size_t)j * 768 + part * 192;
    float acc = 0.f;
    for (int t = 0; t < 192; t += 4) {
        float4 w4 = *(const float4*)(row + t);
        acc = fmaf(w4.x, Ml[part * 192 + t + 0], acc);
        acc = fmaf(w4.y, Ml[part * 192 + t + 1], acc);
        acc = fmaf(w4.z, Ml[part * 192 + t + 2], acc);
        acc = fmaf(w4.w, Ml[part * 192 + t + 3], acc);
    }
    ps[part][jj] = acc;
    __syncthreads();
    if (tid < 64) {
        float s = ps[0][tid] + ps[1][tid] + ps[2][tid] + ps[3][tid] + ob[jt * 64 + tid];
        y[b * 768 + jt * 64 + tid] = s;
    }
}

// ---------------------------------------------------------------------------
// K5b: broadcast y[b][:] to all 1024 sequence rows of the output
// ---------------------------------------------------------------------------
__global__ __launch_bounds__(256) void k_bcast(const float* __restrict__ y,
                                               float* __restrict__ out) {
    const int total = (B_ * S_ * FIN) / 4;
    for (int i = blockIdx.x * 256 + threadIdx.x; i < total; i += gridDim.x * 256) {
        int e0 = i * 4;
        int j = e0 % 768;
        int b = e0 / (1024 * 768);
        float4 v = *(const float4*)(y + b * 768 + j);
        *(float4*)(out + e0) = v;
    }
}

extern "C" void kernel_launch(void* const* d_in, const int* in_sizes, int n_in,
                              void* d_out, int out_size, void* d_ws, size_t ws_size,
                              hipStream_t stream) {
    const float* xs = (const float*)d_in[0];  // [2,1024,768]
    const float* ew = (const float*)d_in[1];  // [768,768]
    const float* eb = (const float*)d_in[2];  // [768]
    const float* nw = (const float*)d_in[3];  // [64,64]
    const float* ow = (const float*)d_in[4];  // [768,768]
    const float* ob = (const float*)d_in[5];  // [768]
    float* out = (float*)d_out;               // [2,1024,768]

    float* ws = (float*)d_ws;
    float* inp = ws;                 // 1572864 floats (dead after k_nnmf)
    float* h   = ws + 1572864;       // 1572864
    float* hri = ws + 3145728;       // 1572864
    // alpha scratch aliases the dead inp region (k_nnmf consumed it first):
    float* c   = inp;                // 24576
    float* mpA = inp + 24576;        // 24576
    float* mpB = inp + 49152;        // 24576
    float* mpM = inp + 73728;        // 24576
    float* y   = inp + 98304;        // 1536

    k_embed<<<dim3(32, 12), 256, 0, stream>>>(xs, ew, eb, inp);
    k_nnmf<<<1536, 256, 0, stream>>>(inp, nw, h, hri);
    k_alpha_step<<<384, 256, 0, stream>>>(h, hri, nw, mpB, mpA, c, 0);
    k_alpha_step<<<384, 256, 0, stream>>>(h, hri, nw, mpA, mpB, c, 1);
    k_alpha_step<<<384, 256, 0, stream>>>(h, hri, nw, mpB, mpA, c, 2);
    k_alpha_step<<<384, 256, 0, stream>>>(h, hri, nw, mpA, mpM, c, 3);
    k_proj<<<24, 256, 0, stream>>>(mpM, ow, ob, y);
    k_bcast<<<384, 256, 0, stream>>>(y, out);
}

// Round 4
// 200.592 us; speedup vs baseline: 1.2870x; 1.0352x over previous
//
#include <hip/hip_runtime.h>

// Problem constants
#define B_  2
#define S_  1024
#define FIN 768
#define E_  768
#define H_  12
#define DH  64   // = FH = 64

typedef unsigned int uint;

__device__ __forceinline__ float bcast_lane(float v, int l) {
    return __uint_as_float((uint)__builtin_amdgcn_readlane((int)__float_as_uint(v), l));
}

__device__ __forceinline__ float wsum64(float v) {
#pragma unroll
    for (int m = 1; m < 64; m <<= 1) v += __shfl_xor(v, m, 64);
    return v;
}

// ---------------------------------------------------------------------------
// K1: normalize nnmf_w rows once: Wn[f][d] = W[f][d]/rowsum, WnT[d][f] = Wn[f][d]
// ---------------------------------------------------------------------------
__global__ __launch_bounds__(256) void k_wprep(const float* __restrict__ nw,
                                               float* __restrict__ Wn,
                                               float* __restrict__ WnT) {
    const int tid = threadIdx.x;
    const int f = tid >> 2, q = tid & 3;      // 4 lanes per row
    float v[16];
    float s = 0.f;
#pragma unroll
    for (int i = 0; i < 16; ++i) { v[i] = nw[f * 64 + q * 16 + i]; s += v[i]; }
    s += __shfl_xor(s, 1, 64);
    s += __shfl_xor(s, 2, 64);
    const float inv = 1.f / fmaxf(s, 1e-20f);
#pragma unroll
    for (int i = 0; i < 16; ++i) {
        float w = v[i] * inv;
        Wn[f * 64 + q * 16 + i] = w;
        WnT[(q * 16 + i) * 64 + f] = w;
    }
}

// ---------------------------------------------------------------------------
// K2 v4: xe = clip(x @ embed_w^T + b, 1e-6); inp = l1norm per (token, head)
// 32 tok x 64 out tiles -> 768 blocks (12 waves/CU). Thread-tile 2x4.
// k-major LDS (26 KB -> 6 blocks/CU). Global prefetch pipelined over compute.
// ---------------------------------------------------------------------------
__global__ __launch_bounds__(256) void k_embed(const float* __restrict__ xs,
                                               const float* __restrict__ ew,
                                               const float* __restrict__ eb,
                                               float* __restrict__ inp) {
    __shared__ float As[64 * 34];   // [k][tok], 8.5 KB
    __shared__ float Bs[64 * 68];   // [k][out], 17 KB
    const int tid = threadIdx.x;
    const int head = blockIdx.y;
    const int tok0 = blockIdx.x * 32;
    const int og = tid & 15;        // out quad (4 outs)
    const int tg = tid >> 4;        // token pair (2 toks)

    float acc[2][4];
#pragma unroll
    for (int i = 0; i < 2; ++i)
#pragma unroll
        for (int j = 0; j < 4; ++j) acc[i][j] = 0.f;

    const int arow = tid & 31, akc = (tid >> 5) * 8;   // A: 32 tok x 8 k
    const int brow = tid & 63, bkc = (tid >> 6) * 16;  // B: 64 out x 16 k
    const float* xrow = xs + (size_t)(tok0 + arow) * FIN + akc;
    const float* wrow = ew + (size_t)(head * 64 + brow) * FIN + bkc;

    float4 pa0 = *(const float4*)(xrow);
    float4 pa1 = *(const float4*)(xrow + 4);
    float4 pb[4];
#pragma unroll
    for (int c = 0; c < 4; ++c) pb[c] = *(const float4*)(wrow + c * 4);

    for (int kb = 0; kb < FIN; kb += 64) {
        __syncthreads();   // previous panel compute done
        As[(akc + 0) * 34 + arow] = pa0.x; As[(akc + 1) * 34 + arow] = pa0.y;
        As[(akc + 2) * 34 + arow] = pa0.z; As[(akc + 3) * 34 + arow] = pa0.w;
        As[(akc + 4) * 34 + arow] = pa1.x; As[(akc + 5) * 34 + arow] = pa1.y;
        As[(akc + 6) * 34 + arow] = pa1.z; As[(akc + 7) * 34 + arow] = pa1.w;
#pragma unroll
        for (int c = 0; c < 4; ++c) {
            int k = bkc + c * 4;
            Bs[(k + 0) * 68 + brow] = pb[c].x; Bs[(k + 1) * 68 + brow] = pb[c].y;
            Bs[(k + 2) * 68 + brow] = pb[c].z; Bs[(k + 3) * 68 + brow] = pb[c].w;
        }
        __syncthreads();
        if (kb + 64 < FIN) {   // issue next panel's loads before compute
            pa0 = *(const float4*)(xrow + kb + 64);
            pa1 = *(const float4*)(xrow + kb + 68);
#pragma unroll
            for (int c = 0; c < 4; ++c) pb[c] = *(const float4*)(wrow + kb + 64 + c * 4);
        }
#pragma unroll 8
        for (int k = 0; k < 64; ++k) {
            float2 a2 = *(const float2*)&As[k * 34 + tg * 2];
            float4 b4 = *(const float4*)&Bs[k * 68 + og * 4];
            acc[0][0] = fmaf(a2.x, b4.x, acc[0][0]);
            acc[0][1] = fmaf(a2.x, b4.y, acc[0][1]);
            acc[0][2] = fmaf(a2.x, b4.z, acc[0][2]);
            acc[0][3] = fmaf(a2.x, b4.w, acc[0][3]);
            acc[1][0] = fmaf(a2.y, b4.x, acc[1][0]);
            acc[1][1] = fmaf(a2.y, b4.y, acc[1][1]);
            acc[1][2] = fmaf(a2.y, b4.z, acc[1][2]);
            acc[1][3] = fmaf(a2.y, b4.w, acc[1][3]);
        }
    }

    // epilogue: bias, clamp, per-token l1norm over 64 outs (shfl over og lanes)
    float4 bias = *(const float4*)(eb + head * 64 + og * 4);
    float bb[4] = {bias.x, bias.y, bias.z, bias.w};
#pragma unroll
    for (int i = 0; i < 2; ++i) {
        float p = 0.f;
#pragma unroll
        for (int j = 0; j < 4; ++j) {
            float xe = fmaxf(acc[i][j] + bb[j], 1e-6f);
            acc[i][j] = xe;
            p += xe;
        }
        p += __shfl_xor(p, 1, 64);
        p += __shfl_xor(p, 2, 64);
        p += __shfl_xor(p, 4, 64);
        p += __shfl_xor(p, 8, 64);
        const float inv = 1.f / fmaxf(p, 1e-20f);
        const int g = tok0 + tg * 2 + i;
        const int b = g >> 10, s = g & 1023;
        float4 o;
        o.x = acc[i][0] * inv; o.y = acc[i][1] * inv;
        o.z = acc[i][2] * inv; o.w = acc[i][3] * inv;
        *(float4*)(inp + ((size_t)((b * 12 + head) * 1024 + s)) * 64 + og * 4) = o;
    }
}

// ---------------------------------------------------------------------------
// K3 v2: NNMF updates, one wave per 4 token-heads. W/WT loaded from global
// (precomputed by k_wprep, L2-hot). Fuses the it=0 alpha partial:
// atomicAdd of per-wave sum(h) into mp0[th>>6][64].
// ---------------------------------------------------------------------------
__global__ __launch_bounds__(256) void k_nnmf(const float* __restrict__ inp,
                                              const float* __restrict__ Wn,
                                              const float* __restrict__ WnT,
                                              float* __restrict__ hout,
                                              float* __restrict__ hriout,
                                              float* __restrict__ mp0) {
    const int tid = threadIdx.x;
    const int lane = tid & 63;
    float wcol[64], wrow[64];
#pragma unroll
    for (int f = 0; f < 64; ++f) wcol[f] = Wn[f * 64 + lane];   // W[f][lane]
#pragma unroll
    for (int d = 0; d < 64; ++d) wrow[d] = WnT[d * 64 + lane];  // W[lane][d]

    const int wid = blockIdx.x * 4 + (tid >> 6);
    float hsum = 0.f;
    for (int tt = 0; tt < 4; ++tt) {
        const int th = wid * 4 + tt;
        const size_t base = (size_t)th * 64;
        float inpv = inp[base + lane];
        float h = 1.f / 64.f;
        float rec = 0.f;
        for (int it = 0; it < 3; ++it) {
            float t0 = 0, t1 = 0, t2 = 0, t3 = 0;
#pragma unroll
            for (int f = 0; f < 64; f += 4) {
                t0 = fmaf(bcast_lane(h, f + 0), wcol[f + 0], t0);
                t1 = fmaf(bcast_lane(h, f + 1), wcol[f + 1], t1);
                t2 = fmaf(bcast_lane(h, f + 2), wcol[f + 2], t2);
                t3 = fmaf(bcast_lane(h, f + 3), wcol[f + 3], t3);
            }
            float t = fmaxf((t0 + t1) + (t2 + t3), 1e-6f);
            rec = t / fmaxf(wsum64(t), 1e-20f);
            float q = inpv / rec;
            float u0 = 0, u1 = 0, u2 = 0, u3 = 0;
#pragma unroll
            for (int d = 0; d < 64; d += 4) {
                u0 = fmaf(bcast_lane(q, d + 0), wrow[d + 0], u0);
                u1 = fmaf(bcast_lane(q, d + 1), wrow[d + 1], u1);
                u2 = fmaf(bcast_lane(q, d + 2), wrow[d + 2], u2);
                u3 = fmaf(bcast_lane(q, d + 3), wrow[d + 3], u3);
            }
            float hn = fmaxf(h * ((u0 + u1) + (u2 + u3)), 1e-6f);
            h = hn / fmaxf(wsum64(hn), 1e-20f);
        }
        h = h / fmaxf(wsum64(h), 1e-20f);
        hout[base + lane] = h;
        hriout[base + lane] = rec * inpv;
        hsum += h;
    }
    // it=0 alpha partial: m0[chunk][f] += sum over this wave's 4 o's
    atomicAdd(&mp0[(size_t)(wid >> 4) * 64 + lane], hsum);
}

// ---------------------------------------------------------------------------
// K4 v4: one alpha iteration per launch, 384 blocks = (bh) x (64-o chunk).
// W from global (precomputed); no W staging, no serial prep.
//   m = sum of 16 chunk partials; v = 1/(mW+eps); c[o] *= hri[o]·v; emit m-partial.
// ---------------------------------------------------------------------------
__global__ __launch_bounds__(256) void k_alpha_step(const float* __restrict__ hin,
                                                    const float* __restrict__ hri,
                                                    const float* __restrict__ Wn,
                                                    const float* __restrict__ mp_in,
                                                    float* __restrict__ mp_out,
                                                    float* __restrict__ c,
                                                    int it) {
    __shared__ float mred[4][64];
    __shared__ float mv[64];
    __shared__ float vv[64];
    __shared__ float cl[64];
    const int tid = threadIdx.x;
    const int bh = blockIdx.x >> 4;
    const int chunk = blockIdx.x & 15;
    const size_t rowbase = (size_t)bh * 1024 + chunk * 64;

    // m[f] = sum over 16 chunks of mp_in[bh][ch][f]
    {
        int f = tid & 63, p = tid >> 6;
        float s = 0.f;
#pragma unroll
        for (int pp = 0; pp < 4; ++pp)
            s += mp_in[((size_t)bh * 16 + p * 4 + pp) * 64 + f];
        mred[p][f] = s;
    }
    __syncthreads();
    if (tid < 64)
        mv[tid] = (mred[0][tid] + mred[1][tid]) + (mred[2][tid] + mred[3][tid]);
    __syncthreads();
    // v[d] = 1/(sum_f m[f]*W[f][d] + eps)
    {
        int d = tid & 63, qq = tid >> 6;
        float r = 0.f;
#pragma unroll
        for (int ff = 0; ff < 16; ++ff)
            r = fmaf(mv[qq * 16 + ff], Wn[(size_t)(qq * 16 + ff) * 64 + d], r);
        mred[qq][d] = r;
    }
    __syncthreads();
    if (tid < 64)
        vv[tid] = 1.f / (((mred[0][tid] + mred[1][tid]) + (mred[2][tid] + mred[3][tid])) + 1e-20f);
    __syncthreads();
    // c-update: c[o] *= dot(hri[o,:], v)
    {
        int o = tid >> 2, dq = tid & 3;
        const float* rp = hri + (rowbase + o) * 64 + dq * 16;
        float dot = 0.f;
#pragma unroll
        for (int t4 = 0; t4 < 16; t4 += 4) {
            float4 r4 = *(const float4*)(rp + t4);
            dot = fmaf(r4.x, vv[dq * 16 + t4 + 0], dot);
            dot = fmaf(r4.y, vv[dq * 16 + t4 + 1], dot);
            dot = fmaf(r4.z, vv[dq * 16 + t4 + 2], dot);
            dot = fmaf(r4.w, vv[dq * 16 + t4 + 3], dot);
        }
        dot += __shfl_xor(dot, 1, 64);
        dot += __shfl_xor(dot, 2, 64);
        float cn = dot;
        if (it >= 2) cn *= c[rowbase + o];
        if (dq == 0) { c[rowbase + o] = cn; cl[o] = cn; }
    }
    __syncthreads();
    // partial m for this chunk: m_c[f] = sum_{o in chunk} h[o,f] * cl[o]
    {
        const int f4 = (tid & 15) * 4, og = tid >> 4;
        float4 a = make_float4(0.f, 0.f, 0.f, 0.f);
#pragma unroll
        for (int oi = 0; oi < 4; ++oi) {
            int o = og * 4 + oi;
            float4 h4 = *(const float4*)(hin + (rowbase + o) * 64 + f4);
            float cv = cl[o];
            a.x = fmaf(h4.x, cv, a.x); a.y = fmaf(h4.y, cv, a.y);
            a.z = fmaf(h4.z, cv, a.z); a.w = fmaf(h4.w, cv, a.w);
        }
        a.x += __shfl_xor(a.x, 16, 64); a.y += __shfl_xor(a.y, 16, 64);
        a.z += __shfl_xor(a.z, 16, 64); a.w += __shfl_xor(a.w, 16, 64);
        a.x += __shfl_xor(a.x, 32, 64); a.y += __shfl_xor(a.y, 32, 64);
        a.z += __shfl_xor(a.z, 32, 64); a.w += __shfl_xor(a.w, 32, 64);
        const int w = tid >> 6;
        if ((tid & 63) < 16) *(float4*)&mred[w][(tid & 15) * 4] = a;
    }
    __syncthreads();
    if (tid < 64)
        mp_out[((size_t)bh * 16 + chunk) * 64 + tid] =
            (mred[0][tid] + mred[1][tid]) + (mred[2][tid] + mred[3][tid]);
}

// ---------------------------------------------------------------------------
// K5: fused out-projection + broadcast. Block (b, jt): y-seg[64] = M[b]@ow^T+ob,
// then store it to all 1024 sequence rows.
// ---------------------------------------------------------------------------
__global__ __launch_bounds__(256) void k_projbcast(const float* __restrict__ mpM,
                                                   const float* __restrict__ ow,
                                                   const float* __restrict__ ob,
                                                   float* __restrict__ out) {
    __shared__ float Ml[768];
    __shared__ float ps[4][64];
    __shared__ float yseg[64];
    const int tid = threadIdx.x;
    const int b = blockIdx.x / 12, jt = blockIdx.x % 12;
    for (int i = tid; i < 768; i += 256) {
        int hh = i >> 6, f = i & 63;
        const float* mp = mpM + ((size_t)(b * 12 + hh) * 16) * 64 + f;
        float s = 0.f;
#pragma unroll
        for (int ch = 0; ch < 16; ++ch) s += mp[ch * 64];
        Ml[i] = s;
    }
    __syncthreads();
    const int jj = tid & 63, part = tid >> 6;
    const int j = jt * 64 + jj;
    const float* row = ow + (size_t)j * 768 + part * 192;
    float acc = 0.f;
    for (int t = 0; t < 192; t += 4) {
        float4 w4 = *(const float4*)(row + t);
        acc = fmaf(w4.x, Ml[part * 192 + t + 0], acc);
        acc = fmaf(w4.y, Ml[part * 192 + t + 1], acc);
        acc = fmaf(w4.z, Ml[part * 192 + t + 2], acc);
        acc = fmaf(w4.w, Ml[part * 192 + t + 3], acc);
    }
    ps[part][jj] = acc;
    __syncthreads();
    if (tid < 64)
        yseg[tid] = ps[0][tid] + ps[1][tid] + ps[2][tid] + ps[3][tid] + ob[jt * 64 + tid];
    __syncthreads();
    // broadcast to all 1024 rows
    const int r0 = tid >> 2, c4 = (tid & 3) * 16;
    float4 v4[4];
#pragma unroll
    for (int q = 0; q < 4; ++q) v4[q] = *(const float4*)&yseg[c4 + q * 4];
#pragma unroll
    for (int rr = 0; rr < 16; ++rr) {
        int rowi = rr * 64 + r0;
        float* dst = out + ((size_t)(b * 1024 + rowi)) * 768 + jt * 64 + c4;
#pragma unroll
        for (int q = 0; q < 4; ++q) *(float4*)(dst + q * 4) = v4[q];
    }
}

extern "C" void kernel_launch(void* const* d_in, const int* in_sizes, int n_in,
                              void* d_out, int out_size, void* d_ws, size_t ws_size,
                              hipStream_t stream) {
    const float* xs = (const float*)d_in[0];  // [2,1024,768]
    const float* ew = (const float*)d_in[1];  // [768,768]
    const float* eb = (const float*)d_in[2];  // [768]
    const float* nw = (const float*)d_in[3];  // [64,64]
    const float* ow = (const float*)d_in[4];  // [768,768]
    const float* ob = (const float*)d_in[5];  // [768]
    float* out = (float*)d_out;               // [2,1024,768]

    float* ws = (float*)d_ws;
    float* inp = ws;                 // 1572864 floats (dead after k_nnmf)
    float* h   = ws + 1572864;       // 1572864
    float* hri = ws + 3145728;       // 1572864
    float* Wn  = ws + 4718592;       // 4096
    float* WnT = ws + 4722688;       // 4096
    float* mp0 = ws + 4726784;       // 24576 (atomic target, must not alias inp)
    // alpha scratch aliasing dead inp region:
    float* c   = inp;                // 24576
    float* mp1 = inp + 24576;        // 24576
    float* mp2 = inp + 49152;        // 24576
    float* mpM = inp + 73728;        // 24576

    hipMemsetAsync(mp0, 0, 24576 * sizeof(float), stream);
    k_wprep<<<1, 256, 0, stream>>>(nw, Wn, WnT);
    k_embed<<<dim3(64, 12), 256, 0, stream>>>(xs, ew, eb, inp);
    k_nnmf<<<1536, 256, 0, stream>>>(inp, Wn, WnT, h, hri, mp0);
    k_alpha_step<<<384, 256, 0, stream>>>(h, hri, Wn, mp0, mp1, c, 1);
    k_alpha_step<<<384, 256, 0, stream>>>(h, hri, Wn, mp1, mp2, c, 2);
    k_alpha_step<<<384, 256, 0, stream>>>(h, hri, Wn, mp2, mpM, c, 3);
    k_projbcast<<<24, 256, 0, stream>>>(mpM, ow, ob, out);
}